// Round 5
// baseline (142.258 us; speedup 1.0000x reference)
//
#include <hip/hip_runtime.h>

// Model: enc linear(37->64)+relu -> BiLSTM(H=64, T=128, B=2048) -> (degenerate
// attention == sum over T) -> 10-step decoder LSTM with constant input -> softmax(11).
//
// Exploits: attention weights are all-ones (softmax over a size-1 axis), so
// fd[b] = sum_t concat(hf,hb)[b,t,:] and att1/att2 are dead. fd@dec_wih.T is
// hoisted out of the decoder loop.
//
// R5: single fused kernel. The block's whole x slice (16 rows x 128 t x 37) is
// staged ONCE, coalesced, into LDS as f16 MFMA-B fragments (151.5 KB -- fits
// 160 KiB LDS). 4 enc waves rebuild e[t+1] per step from LDS (1 ds_read_b128 +
// 5-col tail FMA + 1 MFMA); 8 rec waves run the R2 recurrence from a 4 KB
// double-buffered ebuf. Zero HBM traffic in the 128-step loop. This deletes
// the ~55us enc_linear kernel (R4 accounting) and the 32MB efrag round-trip.

typedef _Float16 f16;
typedef f16 f16x8 __attribute__((ext_vector_type(8)));
typedef f16 f16x4 __attribute__((ext_vector_type(4)));
typedef float f32x4 __attribute__((ext_vector_type(4)));

#define MFMA16(a, b, c) __builtin_amdgcn_mfma_f32_16x16x32_f16(a, b, c, 0, 0, 0)

// gate scales folded into weights: i,f,o -> -log2e ; g -> -2*log2e
// then sig = rcp(1+exp2(y)), tanh = 2*rcp(1+exp2(y)) - 1.
#define NLOG2E  -1.4426950408889634f
#define N2LOG2E -2.8853900817779268f

__device__ __forceinline__ float rcp_(float x) { return __builtin_amdgcn_rcpf(x); }
__device__ __forceinline__ float ex2_(float x) { return __builtin_amdgcn_exp2f(x); }
__device__ __forceinline__ float sigf(float x) { return 1.f / (1.f + __expf(-x)); }
__device__ __forceinline__ float tanhf_fast(float x) {
  float e = __expf(2.f * x);
  return 1.f - 2.f / (e + 1.f);
}

// ---------------- Kernel 1: fused encoder + BiLSTM + fd accumulation --------
// 768 threads = 12 waves: w 0..3 = enc (one per SIMD), w 4..11 = rec (2 m-tiles
// each, gate-interleaved permutation -> 4 gates of cell (b,j) in one lane).
__global__ __launch_bounds__(768, 3) void bilstm_fused_k(
    const float* __restrict__ x, const float* __restrict__ w1,
    const float* __restrict__ b1,
    const float* __restrict__ wih_f, const float* __restrict__ whh_f,
    const float* __restrict__ bih_f, const float* __restrict__ bhh_f,
    const float* __restrict__ wih_b, const float* __restrict__ whh_b,
    const float* __restrict__ bih_b, const float* __restrict__ bhh_b,
    float* __restrict__ fd) {
  const int bid = blockIdx.x;
  const int dir = bid >> 7;
  const int bg = bid & 127;
  const int tid = threadIdx.x;
  const int w = tid >> 6, l = tid & 63;      // w in [0,12)
  const int rho = l & 15, c = l >> 4;
  const int gate = rho & 3, uoff = rho >> 2;

  // LDS: 131072 + 4096 + 4096 + 20480 = 159744 B (<= 160 KiB)
  __shared__ __align__(16) f16 xfrag[128][64][8];   // B-frag of x, k 0..31
  __shared__ __align__(16) f16 hbuf[2][2][64][8];   // double-buffered h frags
  __shared__ __align__(16) f16 ebuf[2][2][64][8];   // double-buffered e frags
  __shared__ f16 xtail[128][16][5];                 // x cols 32..36

  // ---- stage x: 16 rows x 4736 f32 contiguous each = 18944 float4 chunks ----
  {
    const float4* xsrc = (const float4*)(x + (size_t)bg * 16 * 4736);
    for (int cidx = tid; cidx < 18944; cidx += 768) {
      const float4 v = xsrc[cidx];
      const int bb = ((cidx >> 5) * 56680) >> 21;   // cidx / 1184  (row)
      const int f0 = (cidx - bb * 1184) * 4;        // flat (t,k) elem index
      const float vv[4] = {v.x, v.y, v.z, v.w};
#pragma unroll
      for (int e = 0; e < 4; e++) {
        const int f = f0 + e;
        const int tt = (f * 56680) >> 21;           // f / 37 (exact for f<4736)
        const int kk = f - tt * 37;
        const f16 hv = (f16)vv[e];
        if (kk < 32) xfrag[tt][bb | (((kk >> 3) & 3) << 4)][kk & 7] = hv;
        else xtail[tt][bb][kk - 32] = hv;
      }
    }
    int* hz = (int*)hbuf;
    for (int i = tid; i < 1024; i += 768) hz[i] = 0;
  }

  // ---- per-wave setup ----
  const bool enc = (w < 4);
  f16x8 w1a = {};
  float w1t[4][5];
  f32x4 eb0 = {};
  f16x8 aih[2][2], ahh[2][2];
  f32x4 bias[2];

  if (enc) {
    // A-frag of W1: tile rows = units 16w..16w+15, k = 8c+i (k<32)
    const float* pw = w1 + (16 * w + rho) * 37;
#pragma unroll
    for (int i = 0; i < 8; i++) w1a[i] = (f16)pw[8 * c + i];
    // tail cols 32..36 applied post-MFMA on C/D rows (unit = 16w+4c+r)
#pragma unroll
    for (int r = 0; r < 4; r++) {
      const float* pt = w1 + (16 * w + 4 * c + r) * 37 + 32;
#pragma unroll
      for (int i = 0; i < 5; i++) w1t[r][i] = pt[i];
      eb0[r] = b1[16 * w + 4 * c + r];
    }
  } else {
    const int wr = w - 4;
    const float* wih = dir ? wih_b : wih_f;
    const float* whh = dir ? whh_b : whh_f;
    const float* bih = dir ? bih_b : bih_f;
    const float* bhh = dir ? bhh_b : bhh_f;
    const float sA = (gate == 2) ? N2LOG2E : NLOG2E;
#pragma unroll
    for (int q = 0; q < 2; q++) {
      const int m = 2 * wr + q;
      const int n = gate * 64 + 4 * m + uoff;   // permuted gate-row -> W row
#pragma unroll
      for (int ks = 0; ks < 2; ks++) {
        const float* p1 = wih + n * 64 + ks * 32 + c * 8;
        const float* p2 = whh + n * 64 + ks * 32 + c * 8;
        f16x8 v1, v2;
#pragma unroll
        for (int i = 0; i < 8; i++) {
          v1[i] = (f16)(p1[i] * sA);
          v2[i] = (f16)(p2[i] * sA);
        }
        aih[q][ks] = v1;
        ahh[q][ks] = v2;
      }
      const int j = 8 * wr + 4 * q + c;
#pragma unroll
      for (int r = 0; r < 4; r++) {
        const float sr = (r == 2) ? N2LOG2E : NLOG2E;
        bias[q][r] = (bih[64 * r + j] + bhh[64 * r + j]) * sr;
      }
    }
  }

  // e[t] builder (enc waves): 1 aligned b128 frag read + 5-col tail FMA + MFMA
  auto enc_build = [&](int tm, int buf) {
    const f16x8 xb0 = *(const f16x8*)&xfrag[tm][l][0];
    float xt[5];
#pragma unroll
    for (int i = 0; i < 5; i++) xt[i] = (float)xtail[tm][rho][i];
    f32x4 ea = MFMA16(w1a, xb0, eb0);
#pragma unroll
    for (int r = 0; r < 4; r++)
#pragma unroll
      for (int i = 0; i < 5; i++) ea[r] += w1t[r][i] * xt[i];
    f16x4 pk;
#pragma unroll
    for (int r = 0; r < 4; r++) pk[r] = (f16)fmaxf(ea[r], 0.f);
    const int d0 = 16 * w + 4 * c;
    *(f16x4*)&ebuf[buf][w >> 1][rho | (((d0 >> 3) & 3) << 4)][d0 & 7] = pk;
  };

  __syncthreads();  // xfrag/xtail staged, hbuf zeroed

  if (enc) enc_build(dir ? 127 : 0, 0);  // bootstrap e[step 0] into ebuf[0]
  __syncthreads();

  float cst[2] = {0.f, 0.f};
  float hs[2] = {0.f, 0.f};
  const f32x4 z4 = {0.f, 0.f, 0.f, 0.f};

  for (int t = 0; t < 128; t++) {
    const int cur = t & 1, nxt = cur ^ 1;
    if (enc) {
      if (t + 1 < 128) enc_build(dir ? 126 - t : t + 1, nxt);
    } else {
      const f16x8 e0 = *(const f16x8*)&ebuf[cur][0][l][0];
      const f16x8 e1 = *(const f16x8*)&ebuf[cur][1][l][0];
      const f16x8 h0 = *(const f16x8*)&hbuf[cur][0][l][0];
      const f16x8 h1 = *(const f16x8*)&hbuf[cur][1][l][0];
#pragma unroll
      for (int q = 0; q < 2; q++) {
        f32x4 a1 = MFMA16(aih[q][0], e0, bias[q]);
        f32x4 a2 = MFMA16(aih[q][1], e1, z4);
        a1 = MFMA16(ahh[q][0], h0, a1);
        a2 = MFMA16(ahh[q][1], h1, a2);
        const f32x4 a = a1 + a2;
        // pointwise: sig = rcp(1+exp2(y)), tanh = 2*rcp(1+exp2(y)) - 1
        const float ig = rcp_(1.f + ex2_(a[0]));
        const float fg = rcp_(1.f + ex2_(a[1]));
        const float gg = 2.f * rcp_(1.f + ex2_(a[2])) - 1.f;
        const float og = rcp_(1.f + ex2_(a[3]));
        cst[q] = fg * cst[q] + ig * gg;
        const float th = 2.f * rcp_(1.f + ex2_(cst[q] * N2LOG2E)) - 1.f;
        const float h = og * th;
        hs[q] += h;  // fd accumulation (sum over t; reversal irrelevant)
        const int j = 8 * (w - 4) + 4 * q + c;
        hbuf[nxt][j >> 5][rho | (((j >> 3) & 3) << 4)][j & 7] = (f16)h;
      }
    }
    // lgkm-only barrier: all in-loop traffic is LDS.
    asm volatile("s_waitcnt lgkmcnt(0)\n\ts_barrier" ::: "memory");
  }

  if (!enc) {
#pragma unroll
    for (int q = 0; q < 2; q++) {
      const int j = 8 * (w - 4) + 4 * q + c;
      fd[(size_t)(bg * 16 + rho) * 128 + dir * 64 + j] = hs[q];
    }
  }
}

// ---------------- Kernel 2: decoder (10 steps, constant input fd) -----------
__global__ __launch_bounds__(256) void decoder_k(
    const float* __restrict__ fd,
    const float* __restrict__ dwih, const float* __restrict__ dwhh,
    const float* __restrict__ dbih, const float* __restrict__ dbhh,
    const float* __restrict__ dlw, const float* __restrict__ dlb,
    const int* __restrict__ outlen_p, float* __restrict__ out) {
  const int b0 = blockIdx.x * 16;
  const int tid = threadIdx.x;
  const int w = tid >> 6, l = tid & 63;
  const int rho = l & 15, c = l >> 4;
  const int gate = rho & 3, uoff = rho >> 2;
  const int outlen = *outlen_p;

  __shared__ __align__(16) f16 hbuf[2][2][64][8];
  __shared__ float h32[64][16];
  __shared__ float ldslw[11 * 64];
  __shared__ float ldslb[16];
  __shared__ float lg[16][16];

  {
    int* hz = (int*)hbuf;
    for (int i = tid; i < (int)(sizeof(hbuf) / 4); i += 256) hz[i] = 0;
  }
  for (int i = tid; i < 704; i += 256) ldslw[i] = dlw[i];
  if (tid < 16) ldslb[tid] = (tid < 11) ? dlb[tid] : 0.f;

  f16x8 awhh[4][2];
  f32x4 acc0[4];  // bias + fd @ dec_wih^T : constant across steps
  {
    f16x8 bfd[4];
#pragma unroll
    for (int ks = 0; ks < 4; ks++) {
      const float* p = fd + (size_t)(b0 + rho) * 128 + ks * 32 + c * 8;
      f16x8 v;
#pragma unroll
      for (int i = 0; i < 8; i++) v[i] = (f16)p[i];
      bfd[ks] = v;
    }
#pragma unroll
    for (int q = 0; q < 4; q++) {
      const int m = 4 * w + q;
      const int n = gate * 64 + 4 * m + uoff;
      f32x4 a;
      const int j = 16 * w + 4 * q + c;
#pragma unroll
      for (int r = 0; r < 4; r++) a[r] = dbih[64 * r + j] + dbhh[64 * r + j];
#pragma unroll
      for (int ks = 0; ks < 4; ks++) {
        const float* p = dwih + n * 128 + ks * 32 + c * 8;
        f16x8 v;
#pragma unroll
        for (int i = 0; i < 8; i++) v[i] = (f16)p[i];
        a = MFMA16(v, bfd[ks], a);
      }
      acc0[q] = a;
#pragma unroll
      for (int ks = 0; ks < 2; ks++) {
        const float* p = dwhh + n * 64 + ks * 32 + c * 8;
        f16x8 v;
#pragma unroll
        for (int i = 0; i < 8; i++) v[i] = (f16)p[i];
        awhh[q][ks] = v;
      }
    }
  }
  float cst[4] = {0.f, 0.f, 0.f, 0.f};
  __syncthreads();

  for (int s = 0; s < outlen; s++) {
    const int cur = s & 1;
    f16x8 h0 = *(const f16x8*)&hbuf[cur][0][l][0];
    f16x8 h1 = *(const f16x8*)&hbuf[cur][1][l][0];
#pragma unroll
    for (int q = 0; q < 4; q++) {
      f32x4 a = acc0[q];
      a = MFMA16(awhh[q][0], h0, a);
      a = MFMA16(awhh[q][1], h1, a);
      const float ig = sigf(a[0]);
      const float fg = sigf(a[1]);
      const float gg = tanhf_fast(a[2]);
      const float og = sigf(a[3]);
      cst[q] = fg * cst[q] + ig * gg;
      const float h = og * tanhf_fast(cst[q]);
      const int j = 16 * w + 4 * q + c;
      hbuf[cur ^ 1][j >> 5][rho | (((j >> 3) & 3) << 4)][j & 7] = (f16)h;
      h32[j][rho] = h;
    }
    __syncthreads();
    const int b = tid >> 4, o = tid & 15;
    float logit = 0.f;
    if (o < 11) {
      logit = ldslb[o];
      for (int jj = 0; jj < 64; jj++) logit += h32[jj][b] * ldslw[o * 64 + jj];
      lg[b][o] = logit;
    }
    __syncthreads();
    if (o < 11) {
      float mx = lg[b][0];
      for (int k = 1; k < 11; k++) mx = fmaxf(mx, lg[b][k]);
      float sum = 0.f;
      for (int k = 0; k < 11; k++) sum += __expf(lg[b][k] - mx);
      out[(size_t)(b0 + b) * outlen * 11 + (size_t)s * 11 + o] =
          __expf(logit - mx) / sum;
    }
    __syncthreads();
  }
}

extern "C" void kernel_launch(void* const* d_in, const int* in_sizes, int n_in,
                              void* d_out, int out_size, void* d_ws, size_t ws_size,
                              hipStream_t stream) {
  const float* x = (const float*)d_in[0];
  const float* w1 = (const float*)d_in[1];
  const float* b1 = (const float*)d_in[2];
  const float* wih_f = (const float*)d_in[3];
  const float* whh_f = (const float*)d_in[4];
  const float* bih_f = (const float*)d_in[5];
  const float* bhh_f = (const float*)d_in[6];
  const float* wih_b = (const float*)d_in[7];
  const float* whh_b = (const float*)d_in[8];
  const float* bih_b = (const float*)d_in[9];
  const float* bhh_b = (const float*)d_in[10];
  // d_in[11..14]: attention weights — provably dead (softmax over size-1 axis)
  const float* dwih = (const float*)d_in[15];
  const float* dwhh = (const float*)d_in[16];
  const float* dbih = (const float*)d_in[17];
  const float* dbhh = (const float*)d_in[18];
  const float* dlw = (const float*)d_in[19];
  const float* dlb = (const float*)d_in[20];
  const int* outlen = (const int*)d_in[21];
  float* out = (float*)d_out;

  float* fd = (float*)d_ws;  // 1 MB

  hipLaunchKernelGGL(bilstm_fused_k, dim3(256), dim3(768), 0, stream,
                     x, w1, b1, wih_f, whh_f, bih_f, bhh_f,
                     wih_b, whh_b, bih_b, bhh_b, fd);
  hipLaunchKernelGGL(decoder_k, dim3(128), dim3(256), 0, stream,
                     fd, dwih, dwhh, dbih, dbhh, dlw, dlb, outlen, out);
}